// Round 5
// baseline (860.447 us; speedup 1.0000x reference)
//
#include <hip/hip_runtime.h>
#include <hip/hip_bf16.h>
#include <stdint.h>

// ---- constants for this problem ----
// B=4, S=4096, D=1024, M=4096. DECAY=0.9
#define BSZ 4
#define SEQ 4096
#define DIM 1024
#define MDIM 4096
#define DECAYF 0.9f
#define OMD 0.1f
#define CHUNK 128
#define NCHUNK 32           // SEQ / CHUNK
#define DECAY_CHUNK 1.3901844577868923e-06f  // 0.9^128

typedef __bf16 bf16_t;
typedef __bf16 bf16x8 __attribute__((ext_vector_type(8)));
typedef __bf16 bf16x4 __attribute__((ext_vector_type(4)));
typedef float floatx4 __attribute__((ext_vector_type(4)));

// ---- async global->LDS, 16B per lane. lds ptr must be wave-uniform base;
//      HW writes lane i at base + i*16 (m97 pattern). ----
__device__ __forceinline__ void load16_lds(const void* g, void* l) {
  __builtin_amdgcn_global_load_lds(
      (__attribute__((address_space(1))) void*)g,
      (__attribute__((address_space(3))) void*)l,
      16, 0, 0);
}

// ---------------- scan kernels ----------------
// Pass 1: chunk-end partial sums. Only the last 64 elements matter:
// neglected terms are scaled by 0.9^64 ~= 1.2e-3 (below bf16 ulp of prev).
__global__ void scan_chunk_kernel(const float* __restrict__ x,
                                  float* __restrict__ chunk_end) {
  int t = blockIdx.x * 256 + threadIdx.x;
  int d = t & (DIM - 1);
  int c = (t >> 10) & (NCHUNK - 1);
  int b = t >> 15;
  const float* xp = x + ((size_t)(b * SEQ + c * CHUNK + 64)) * DIM + d;
  float p = 0.f;
#pragma unroll 8
  for (int s = 0; s < 64; ++s) p = DECAYF * p + OMD * xp[(size_t)s * DIM];
  chunk_end[t] = p;
}

__global__ void scan_carry_kernel(const float* __restrict__ chunk_end,
                                  float* __restrict__ carry_in,
                                  float* __restrict__ final_state) {
  int t = blockIdx.x * 256 + threadIdx.x;
  int d = t & (DIM - 1);
  int b = t >> 10;
  float carry = 0.f;
#pragma unroll
  for (int c = 0; c < NCHUNK; ++c) {
    int idx = (b * NCHUNK + c) * DIM + d;
    carry_in[idx] = carry;
    carry = carry * DECAY_CHUNK + chunk_end[idx];
  }
  final_state[t] = carry;  // == current_states[b, S-1, d]
}

__global__ void scan_emit_kernel(const float* __restrict__ x,
                                 const float* __restrict__ carry_in,
                                 bf16_t* __restrict__ prev) {
  int t = blockIdx.x * 256 + threadIdx.x;
  int d = t & (DIM - 1);
  int c = (t >> 10) & (NCHUNK - 1);
  int b = t >> 15;
  size_t base = ((size_t)(b * SEQ + c * CHUNK)) * DIM + d;
  const float* xp = x + base;
  bf16_t* pp = prev + base;
  float cs = carry_in[t];  // == current_states[b, c*CHUNK - 1, d]
#pragma unroll 4
  for (int s = 0; s < CHUNK; ++s) {
    pp[(size_t)s * DIM] = (bf16_t)cs;   // prev[t] = cs[t-1]
    cs = DECAYF * cs + OMD * xp[(size_t)s * DIM];
  }
}

// ---------------- fp32 -> bf16 convert (4 elems / thread) ----------------
__global__ void cvt_bf16_kernel(const float* __restrict__ w, bf16_t* __restrict__ o) {
  int t = blockIdx.x * 256 + threadIdx.x;
  float4 v = ((const float4*)w)[t];
  bf16x4 r = { (bf16_t)v.x, (bf16_t)v.y, (bf16_t)v.z, (bf16_t)v.w };
  ((bf16x4*)o)[t] = r;
}

// ---------------- GEMM: C[M][N] = A[M][K] * B[N][K]^T  (both K-contiguous bf16)
// 128x128 tile, 256 threads (4 waves, each 64x64), 16x16x32 bf16 MFMA.
// R5 pipeline (fixes R4's vmcnt chaining: A-loads issued AFTER stageB made
// every MFMA wait transitively drain next-half staging -> full serialization,
// MfmaUtil 15.7%):
//  - A-fragments direct global->VGPR, double-buffered ACROSS the barrier:
//    per half we issue stage(next)+loadA(next), then compute the CURRENT half
//    entirely from registers drained by this half's barrier. Compute has no
//    vmcnt waits at all; the barrier's vmcnt(0) drain covers loads issued a
//    full compute phase earlier.
//  - LDS holds only B (2 x 16KB buffers): 48KB LDS traffic/half vs R3's 96KB
//    -> MFMA (621 cyc/half) is the binding pipe, not LDS.
// B-side LDS keeps the XOR swizzle (R2: conflicts 5e7 -> 0).
// XCD-aware 1D grid remap (R3: A-tile sharers land on one XCD's L2).
// EPI==0: silu -> bf16 store.  EPI==1: fp32 store + fused MSE partial vs X.
template <int N, int K, int MT, int EPI>
__global__ __launch_bounds__(256, 3) void gemm_bt_kernel(
    const bf16_t* __restrict__ A, const bf16_t* __restrict__ B,
    void* __restrict__ Cout, const float* __restrict__ X,
    float* __restrict__ loss_acc) {
  constexpr int NT = N / 128;
  __shared__ __attribute__((aligned(16))) bf16_t sB0[128 * 64];
  __shared__ __attribute__((aligned(16))) bf16_t sB1[128 * 64];

  const int tid = threadIdx.x;
  const int wave = tid >> 6;
  const int lane = tid & 63;
  const int bid = blockIdx.x;
  const int xcd = bid & 7;
  const int slot = bid >> 3;
  const int tm = (xcd * (MT / 8) + slot / NT) * 128;
  const int tn = (slot % NT) * 128;
  const int lrow = lane >> 3;                    // row within 8-row staging group
  const int lcol = ((lane & 7) ^ lrow) * 8;      // swizzled source chunk
  const int wm = (wave & 1) * 64;                // wave sub-tile origin
  const int wn = (wave >> 1) * 64;

  // A-fragment base: row = tm+wm+i*16+(lane&15), k = kt + ks*32 + (lane>>4)*8
  const bf16_t* arow = A + (size_t)(tm + wm + (lane & 15)) * K + ((lane >> 4) * 8);

  floatx4 acc[4][4];
#pragma unroll
  for (int i = 0; i < 4; ++i)
#pragma unroll
    for (int j = 0; j < 4; ++j) acc[i][j] = (floatx4){0.f, 0.f, 0.f, 0.f};

  auto stageB = [&](int kt2, bf16_t* buf) {
#pragma unroll
    for (int j = 0; j < 4; ++j) {
      const int g = j * 4 + wave;  // 16 groups of 8 rows
      load16_lds(B + (size_t)(tn + g * 8 + lrow) * K + kt2 + lcol,
                 (char*)buf + g * 1024);
    }
  };

  auto loadA = [&](int kt2, bf16x8 (&af)[2][4]) {
#pragma unroll
    for (int ks = 0; ks < 2; ++ks)
#pragma unroll
      for (int i = 0; i < 4; ++i)
        af[ks][i] = *(const bf16x8*)(arow + (size_t)i * 16 * K + kt2 + ks * 32);
  };

  auto computeHalf = [&](const bf16_t* buf, const bf16x8 (&af)[2][4]) {
#pragma unroll
    for (int ks = 0; ks < 2; ++ks) {
      // logical chunk = ks*4 + (lane>>4); row&7 == lane&7 for every fragment.
      const int pchunk = (((ks * 4) + (lane >> 4)) ^ (lane & 7)) * 8;
      bf16x8 bfr[4];
#pragma unroll
      for (int j = 0; j < 4; ++j)
        bfr[j] = *(const bf16x8*)&buf[(size_t)(wn + j * 16 + (lane & 15)) * 64 + pchunk];
#pragma unroll
      for (int i = 0; i < 4; ++i)
#pragma unroll
        for (int j = 0; j < 4; ++j)
          acc[i][j] = __builtin_amdgcn_mfma_f32_16x16x32_bf16(af[ks][i], bfr[j],
                                                              acc[i][j], 0, 0, 0);
    }
  };

  bf16x8 afX[2][4], afY[2][4];
  stageB(0, sB0);
  loadA(0, afX);   // prologue: chained behind stage(0); both drained by 1st barrier
#pragma unroll 1
  for (int kt = 0; kt < K; kt += 128) {
    // half 0: sB0/afX ready after barrier; prefetch half 1 (sB1/afY)
    __syncthreads();
    stageB(kt + 64, sB1);
    loadA(kt + 64, afY);
    computeHalf(sB0, afX);
    // half 1: sB1/afY ready after barrier; prefetch next iter's half 0
    __syncthreads();
    if (kt + 128 < K) {
      stageB(kt + 128, sB0);
      loadA(kt + 128, afX);
    }
    computeHalf(sB1, afY);
  }

  // epilogue. C/D frag: col = lane&15, row = (lane>>4)*4 + reg
  const int r0 = (lane >> 4) * 4;
  const int cn = lane & 15;
  if constexpr (EPI == 0) {
    bf16_t* H = (bf16_t*)Cout;
#pragma unroll
    for (int i = 0; i < 4; ++i)
#pragma unroll
      for (int j = 0; j < 4; ++j)
#pragma unroll
        for (int r = 0; r < 4; ++r) {
          int m = tm + wm + i * 16 + r0 + r;
          int n = tn + wn + j * 16 + cn;
          float v = acc[i][j][r];
          v = v / (1.f + __expf(-v));  // silu
          H[(size_t)m * N + n] = (bf16_t)v;
        }
  } else {
    float* O = (float*)Cout;
    float ls = 0.f;
#pragma unroll
    for (int i = 0; i < 4; ++i)
#pragma unroll
      for (int j = 0; j < 4; ++j)
#pragma unroll
        for (int r = 0; r < 4; ++r) {
          int m = tm + wm + i * 16 + r0 + r;
          int n = tn + wn + j * 16 + cn;
          size_t off = (size_t)m * N + n;
          float v = acc[i][j][r];
          O[off] = v;
          float dd = v - X[off];
          ls += dd * dd;
        }
    // wave reduction then one atomic per wave
#pragma unroll
    for (int s = 32; s > 0; s >>= 1) ls += __shfl_down(ls, s, 64);
    if (lane == 0) atomicAdd(loss_acc, ls);
  }
}

__global__ void finalize_loss_kernel(const float* __restrict__ loss_acc,
                                     float* __restrict__ out) {
  if (threadIdx.x == 0)
    out[0] = loss_acc[0] * (1.0f / (float)(BSZ * SEQ * DIM));
}

// ---------------- launch ----------------
extern "C" void kernel_launch(void* const* d_in, const int* in_sizes, int n_in,
                              void* d_out, int out_size, void* d_ws, size_t ws_size,
                              hipStream_t stream) {
  const float* x  = (const float*)d_in[0];   // [4][4096][1024]
  const float* w1 = (const float*)d_in[1];   // [4096][1024]
  const float* w2 = (const float*)d_in[2];   // [1024][4096]
  float* out = (float*)d_out;                // mem_out | loss | final_state

  const int BT = BSZ * SEQ;                  // 16384 rows, 128 m-tiles
  char* ws = (char*)d_ws;
  // workspace layout (bytes)
  bf16_t* prev      = (bf16_t*)(ws);                      // 16M bf16  = 33,554,432 B
  bf16_t* h         = (bf16_t*)(ws + 33554432ull);        // 64M bf16  = 134,217,728 B
  bf16_t* w1b       = (bf16_t*)(ws + 167772160ull);       // 4M bf16   = 8,388,608 B
  bf16_t* w2b       = (bf16_t*)(ws + 176160768ull);       // 4M bf16   = 8,388,608 B
  float*  chunk_end = (float*)(ws + 184549376ull);        // 128K f32  = 524,288 B
  float*  carry_in  = (float*)(ws + 185073664ull);        // 128K f32  = 524,288 B
  float*  loss_acc  = (float*)(ws + 185597952ull);        // 4 B

  hipMemsetAsync(loss_acc, 0, sizeof(float), stream);

  // weights -> bf16 (4,194,304 elems each; 4/thread)
  cvt_bf16_kernel<<<4096, 256, 0, stream>>>(w1, w1b);
  cvt_bf16_kernel<<<4096, 256, 0, stream>>>(w2, w2b);

  // chunked EMA scan -> prev states (bf16) + final_state (fp32, d_out tail)
  scan_chunk_kernel<<<(BSZ * NCHUNK * DIM) / 256, 256, 0, stream>>>(x, chunk_end);
  scan_carry_kernel<<<(BSZ * DIM) / 256, 256, 0, stream>>>(chunk_end, carry_in,
                                                           out + 16777217);
  scan_emit_kernel<<<(BSZ * NCHUNK * DIM) / 256, 256, 0, stream>>>(x, carry_in, prev);

  // h = silu(prev @ w1^T)  : [16384 x 1024] x [4096 x 1024]^T -> bf16 [16384 x 4096]
  gemm_bt_kernel<MDIM, DIM, BT / 128, 0>
      <<<(BT / 128) * (MDIM / 128), 256, 0, stream>>>(prev, w1b, h, nullptr, nullptr);

  // mem_out = h @ w2^T : [16384 x 4096] x [1024 x 4096]^T -> fp32 [16384 x 1024]
  // fused: loss partial sums vs x
  gemm_bt_kernel<DIM, MDIM, BT / 128, 1>
      <<<(BT / 128) * (DIM / 128), 256, 0, stream>>>(h, w2b, out, x, loss_acc);

  finalize_loss_kernel<<<1, 64, 0, stream>>>(loss_acc, out + 16777216);
}

// Round 6
// 500.574 us; speedup vs baseline: 1.7189x; 1.7189x over previous
//
#include <hip/hip_runtime.h>
#include <hip/hip_bf16.h>
#include <stdint.h>

// ---- constants for this problem ----
// B=4, S=4096, D=1024, M=4096. DECAY=0.9
#define BSZ 4
#define SEQ 4096
#define DIM 1024
#define MDIM 4096
#define DECAYF 0.9f
#define OMD 0.1f
#define CHUNK 128
#define NCHUNK 32           // SEQ / CHUNK
#define DECAY_CHUNK 1.3901844577868923e-06f  // 0.9^128

typedef __bf16 bf16_t;
typedef __bf16 bf16x8 __attribute__((ext_vector_type(8)));
typedef __bf16 bf16x4 __attribute__((ext_vector_type(4)));
typedef float floatx4 __attribute__((ext_vector_type(4)));

// ---- async global->LDS, 16B per lane. lds ptr must be wave-uniform base;
//      HW writes lane i at base + i*16 (m97 pattern). ----
__device__ __forceinline__ void load16_lds(const void* g, void* l) {
  __builtin_amdgcn_global_load_lds(
      (__attribute__((address_space(1))) void*)g,
      (__attribute__((address_space(3))) void*)l,
      16, 0, 0);
}

// ---------------- scan kernels ----------------
// Pass 1: chunk-end partial sums. Only the last 64 elements matter:
// neglected terms are scaled by 0.9^64 ~= 1.2e-3 (below bf16 ulp of prev).
__global__ void scan_chunk_kernel(const float* __restrict__ x,
                                  float* __restrict__ chunk_end) {
  int t = blockIdx.x * 256 + threadIdx.x;
  int d = t & (DIM - 1);
  int c = (t >> 10) & (NCHUNK - 1);
  int b = t >> 15;
  const float* xp = x + ((size_t)(b * SEQ + c * CHUNK + 64)) * DIM + d;
  float p = 0.f;
#pragma unroll 8
  for (int s = 0; s < 64; ++s) p = DECAYF * p + OMD * xp[(size_t)s * DIM];
  chunk_end[t] = p;
}

__global__ void scan_carry_kernel(const float* __restrict__ chunk_end,
                                  float* __restrict__ carry_in,
                                  float* __restrict__ final_state) {
  int t = blockIdx.x * 256 + threadIdx.x;
  int d = t & (DIM - 1);
  int b = t >> 10;
  float carry = 0.f;
#pragma unroll
  for (int c = 0; c < NCHUNK; ++c) {
    int idx = (b * NCHUNK + c) * DIM + d;
    carry_in[idx] = carry;
    carry = carry * DECAY_CHUNK + chunk_end[idx];
  }
  final_state[t] = carry;  // == current_states[b, S-1, d]
}

__global__ void scan_emit_kernel(const float* __restrict__ x,
                                 const float* __restrict__ carry_in,
                                 bf16_t* __restrict__ prev) {
  int t = blockIdx.x * 256 + threadIdx.x;
  int d = t & (DIM - 1);
  int c = (t >> 10) & (NCHUNK - 1);
  int b = t >> 15;
  size_t base = ((size_t)(b * SEQ + c * CHUNK)) * DIM + d;
  const float* xp = x + base;
  bf16_t* pp = prev + base;
  float cs = carry_in[t];  // == current_states[b, c*CHUNK - 1, d]
#pragma unroll 4
  for (int s = 0; s < CHUNK; ++s) {
    pp[(size_t)s * DIM] = (bf16_t)cs;   // prev[t] = cs[t-1]
    cs = DECAYF * cs + OMD * xp[(size_t)s * DIM];
  }
}

// ---------------- fp32 -> bf16 convert (4 elems / thread) ----------------
__global__ void cvt_bf16_kernel(const float* __restrict__ w, bf16_t* __restrict__ o) {
  int t = blockIdx.x * 256 + threadIdx.x;
  float4 v = ((const float4*)w)[t];
  bf16x4 r = { (bf16_t)v.x, (bf16_t)v.y, (bf16_t)v.z, (bf16_t)v.w };
  ((bf16x4*)o)[t] = r;
}

// ---------------- GEMM: C[M][N] = A[M][K] * B[N][K]^T  (both K-contiguous bf16)
// 128x128 tile, BK=64, 256 threads (4 waves, each 64x64), 16x16x32 bf16 MFMA.
// R6 = R3's proven data path (ALL operands via global_load_lds DMA -> LDS;
// compute phase has ZERO vmem instructions, so no vmcnt chaining is possible
// -- the R4/R5 direct-A failures) + double-buffered LDS prefetch:
//   stage(0->buf0); { barrier; stage(next->buf1); compute(buf0); ... }
// Each barrier's vmcnt(0) drain waits on DMA issued a full compute phase
// (~600+ cyc) earlier instead of 0 cyc earlier (R3) -> covers the ~900-cyc
// HBM latency of streamed A (h = 134 MB in GEMM2).
// LDS 64KB -> 2 blocks/CU, same as the VGPR bracket already allowed in R3.
// B/A LDS keeps the XOR swizzle (R2: conflicts 5e7 -> 0).
// XCD-aware 1D grid remap (R3: A-tile sharers land on one XCD's L2).
// EPI==0: silu -> bf16 store.  EPI==1: fp32 store + fused MSE partial vs X.
template <int N, int K, int MT, int EPI>
__global__ __launch_bounds__(256) void gemm_bt_kernel(
    const bf16_t* __restrict__ A, const bf16_t* __restrict__ B,
    void* __restrict__ Cout, const float* __restrict__ X,
    float* __restrict__ loss_acc) {
  constexpr int NT = N / 128;
  __shared__ __attribute__((aligned(16))) bf16_t sA0[128 * 64];
  __shared__ __attribute__((aligned(16))) bf16_t sB0[128 * 64];
  __shared__ __attribute__((aligned(16))) bf16_t sA1[128 * 64];
  __shared__ __attribute__((aligned(16))) bf16_t sB1[128 * 64];

  const int tid = threadIdx.x;
  const int wave = tid >> 6;
  const int lane = tid & 63;
  const int bid = blockIdx.x;
  const int xcd = bid & 7;
  const int slot = bid >> 3;
  const int tm = (xcd * (MT / 8) + slot / NT) * 128;
  const int tn = (slot % NT) * 128;
  const int lrow = lane >> 3;                    // row within 8-row staging group
  const int lcol = ((lane & 7) ^ lrow) * 8;      // swizzled source chunk
  const int wm = (wave & 1) * 64;                // wave sub-tile origin
  const int wn = (wave >> 1) * 64;

  floatx4 acc[4][4];
#pragma unroll
  for (int i = 0; i < 4; ++i)
#pragma unroll
    for (int j = 0; j < 4; ++j) acc[i][j] = (floatx4){0.f, 0.f, 0.f, 0.f};

  auto stage = [&](int kt2, bf16_t* bufA, bf16_t* bufB) {
#pragma unroll
    for (int j = 0; j < 4; ++j) {
      const int g = j * 4 + wave;  // 16 groups of 8 rows
      load16_lds(A + (size_t)(tm + g * 8 + lrow) * K + kt2 + lcol,
                 (char*)bufA + g * 1024);
      load16_lds(B + (size_t)(tn + g * 8 + lrow) * K + kt2 + lcol,
                 (char*)bufB + g * 1024);
    }
  };

  auto computeHalf = [&](const bf16_t* bufA, const bf16_t* bufB) {
#pragma unroll
    for (int ks = 0; ks < 2; ++ks) {
      // logical chunk = ks*4 + (lane>>4); row&7 == lane&7 for every fragment.
      const int pchunk = (((ks * 4) + (lane >> 4)) ^ (lane & 7)) * 8;
      bf16x8 af[4], bfr[4];
#pragma unroll
      for (int i = 0; i < 4; ++i)
        af[i] = *(const bf16x8*)&bufA[(size_t)(wm + i * 16 + (lane & 15)) * 64 + pchunk];
#pragma unroll
      for (int j = 0; j < 4; ++j)
        bfr[j] = *(const bf16x8*)&bufB[(size_t)(wn + j * 16 + (lane & 15)) * 64 + pchunk];
#pragma unroll
      for (int i = 0; i < 4; ++i)
#pragma unroll
        for (int j = 0; j < 4; ++j)
          acc[i][j] = __builtin_amdgcn_mfma_f32_16x16x32_bf16(af[i], bfr[j],
                                                              acc[i][j], 0, 0, 0);
    }
  };

  stage(0, sA0, sB0);
#pragma unroll 1
  for (int kt = 0; kt < K; kt += 128) {
    // barrier drains stage(kt -> buf0), issued one full compute phase ago
    // (prologue excepted), and fences buf1's previous-iter reads.
    __syncthreads();
    if (kt + 64 < K) stage(kt + 64, sA1, sB1);
    computeHalf(sA0, sB0);
    __syncthreads();
    if (kt + 128 < K) stage(kt + 128, sA0, sB0);
    computeHalf(sA1, sB1);
  }

  // epilogue. C/D frag: col = lane&15, row = (lane>>4)*4 + reg
  const int r0 = (lane >> 4) * 4;
  const int cn = lane & 15;
  if constexpr (EPI == 0) {
    bf16_t* H = (bf16_t*)Cout;
#pragma unroll
    for (int i = 0; i < 4; ++i)
#pragma unroll
      for (int j = 0; j < 4; ++j)
#pragma unroll
        for (int r = 0; r < 4; ++r) {
          int m = tm + wm + i * 16 + r0 + r;
          int n = tn + wn + j * 16 + cn;
          float v = acc[i][j][r];
          v = v / (1.f + __expf(-v));  // silu
          H[(size_t)m * N + n] = (bf16_t)v;
        }
  } else {
    float* O = (float*)Cout;
    float ls = 0.f;
#pragma unroll
    for (int i = 0; i < 4; ++i)
#pragma unroll
      for (int j = 0; j < 4; ++j)
#pragma unroll
        for (int r = 0; r < 4; ++r) {
          int m = tm + wm + i * 16 + r0 + r;
          int n = tn + wn + j * 16 + cn;
          size_t off = (size_t)m * N + n;
          float v = acc[i][j][r];
          O[off] = v;
          float dd = v - X[off];
          ls += dd * dd;
        }
    // wave reduction then one atomic per wave
#pragma unroll
    for (int s = 32; s > 0; s >>= 1) ls += __shfl_down(ls, s, 64);
    if (lane == 0) atomicAdd(loss_acc, ls);
  }
}

__global__ void finalize_loss_kernel(const float* __restrict__ loss_acc,
                                     float* __restrict__ out) {
  if (threadIdx.x == 0)
    out[0] = loss_acc[0] * (1.0f / (float)(BSZ * SEQ * DIM));
}

// ---------------- launch ----------------
extern "C" void kernel_launch(void* const* d_in, const int* in_sizes, int n_in,
                              void* d_out, int out_size, void* d_ws, size_t ws_size,
                              hipStream_t stream) {
  const float* x  = (const float*)d_in[0];   // [4][4096][1024]
  const float* w1 = (const float*)d_in[1];   // [4096][1024]
  const float* w2 = (const float*)d_in[2];   // [1024][4096]
  float* out = (float*)d_out;                // mem_out | loss | final_state

  const int BT = BSZ * SEQ;                  // 16384 rows, 128 m-tiles
  char* ws = (char*)d_ws;
  // workspace layout (bytes)
  bf16_t* prev      = (bf16_t*)(ws);                      // 16M bf16  = 33,554,432 B
  bf16_t* h         = (bf16_t*)(ws + 33554432ull);        // 64M bf16  = 134,217,728 B
  bf16_t* w1b       = (bf16_t*)(ws + 167772160ull);       // 4M bf16   = 8,388,608 B
  bf16_t* w2b       = (bf16_t*)(ws + 176160768ull);       // 4M bf16   = 8,388,608 B
  float*  chunk_end = (float*)(ws + 184549376ull);        // 128K f32  = 524,288 B
  float*  carry_in  = (float*)(ws + 185073664ull);        // 128K f32  = 524,288 B
  float*  loss_acc  = (float*)(ws + 185597952ull);        // 4 B

  hipMemsetAsync(loss_acc, 0, sizeof(float), stream);

  // weights -> bf16 (4,194,304 elems each; 4/thread)
  cvt_bf16_kernel<<<4096, 256, 0, stream>>>(w1, w1b);
  cvt_bf16_kernel<<<4096, 256, 0, stream>>>(w2, w2b);

  // chunked EMA scan -> prev states (bf16) + final_state (fp32, d_out tail)
  scan_chunk_kernel<<<(BSZ * NCHUNK * DIM) / 256, 256, 0, stream>>>(x, chunk_end);
  scan_carry_kernel<<<(BSZ * DIM) / 256, 256, 0, stream>>>(chunk_end, carry_in,
                                                           out + 16777217);
  scan_emit_kernel<<<(BSZ * NCHUNK * DIM) / 256, 256, 0, stream>>>(x, carry_in, prev);

  // h = silu(prev @ w1^T)  : [16384 x 1024] x [4096 x 1024]^T -> bf16 [16384 x 4096]
  gemm_bt_kernel<MDIM, DIM, BT / 128, 0>
      <<<(BT / 128) * (MDIM / 128), 256, 0, stream>>>(prev, w1b, h, nullptr, nullptr);

  // mem_out = h @ w2^T : [16384 x 4096] x [1024 x 4096]^T -> fp32 [16384 x 1024]
  // fused: loss partial sums vs x
  gemm_bt_kernel<DIM, MDIM, BT / 128, 1>
      <<<(BT / 128) * (DIM / 128), 256, 0, stream>>>(h, w2b, out, x, loss_acc);

  finalize_loss_kernel<<<1, 64, 0, stream>>>(loss_acc, out + 16777216);
}